// Round 12
// baseline (449.486 us; speedup 1.0000x reference)
//
#include <hip/hip_runtime.h>
#include <hip/hip_bf16.h>

typedef unsigned short u16;
typedef unsigned int   u32;
typedef __attribute__((ext_vector_type(8))) short  s16x8;
typedef __attribute__((ext_vector_type(4))) float  f32x4;
typedef __attribute__((ext_vector_type(4))) unsigned short u16x4;

#define MT    8192   // B*S tokens
#define DE    2048   // embed dim
#define NEXP  64     // experts
#define ERDIM 4096   // experts * rank

__device__ __forceinline__ u16 to_bf16(float f) {
  u32 u = __builtin_bit_cast(u32, f);
  u32 r = u + 0x7fffu + ((u >> 16) & 1u);
  return (u16)(r >> 16);
}

// one launch: convert x, w_up, w_dn f32 -> bf16 (grid-stride each)
__global__ void cvt_all(const float* __restrict__ x,  u16* __restrict__ xo,
                        const float* __restrict__ wu, u16* __restrict__ wuo,
                        const float* __restrict__ wd, u16* __restrict__ wdo) {
  const int stride = gridDim.x * blockDim.x;
  const int t0 = blockIdx.x * blockDim.x + threadIdx.x;
#define CVT_LOOP(src, dst, nq)                                                \
  for (int i = t0; i < (nq); i += stride) {                                   \
    const float4 v = *reinterpret_cast<const float4*>((src) + (size_t)i * 4); \
    u16x4 o;                                                                  \
    o.x = to_bf16(v.x); o.y = to_bf16(v.y);                                   \
    o.z = to_bf16(v.z); o.w = to_bf16(v.w);                                   \
    *reinterpret_cast<u16x4*>((dst) + (size_t)i * 4) = o;                     \
  }
  CVT_LOOP(x,  xo,  (MT * DE) / 4)
  CVT_LOOP(wu, wuo, (ERDIM * DE) / 4)
  CVT_LOOP(wd, wdo, (DE * ERDIM) / 4)
#undef CVT_LOOP
}

#define GLDS(gp, lp) __builtin_amdgcn_global_load_lds(                        \
    (const __attribute__((address_space(1))) void*)(gp),                      \
    (__attribute__((address_space(3))) void*)(lp), 16, 0, 0)

#define BAR() do { asm volatile("" ::: "memory");                             \
                   __builtin_amdgcn_s_barrier();                              \
                   asm volatile("" ::: "memory"); } while (0)

// C = A[M,K] * B[N,K]^T (bf16, row-major). 256x256 tile, BK=32, **16 waves**
// (1024 threads, 4Mx4N wave grid, 64x64 per wave -> 4 waves/SIMD for latency
// hiding -- the one untested axis; everything else is the R3-proven schedule:
// 4-slot LDS ring (128 KiB), prefetch distance 3, counted vmcnt (4/2/0 cascade,
// never 0 mid-loop), ONE barrier per K-tile, free-running waves, setprio MFMA).
// Staging: 1024 threads x 16B = one full 256x32 matrix half per GLDS ->
// 2 GLDS per thread per tile. Linear LDS dest + inverse-swizzled global source;
// reads use matching granule XOR (0 conflicts measured R2-R10).
// Slot safety: GLDS(t+3) targets slot (t-1)&3 whose readers finished before
// barrier(t-1), which precedes these GLDS in program order; vmcnt(4) at tile
// end retires tile t+1's 2 loads before its post-barrier reads.
// FUSE=1: C_bf16[m,n] = bf16( silu(acc) * mask[m, n>>6] );  FUSE=0: C_f32 = acc
template<int FUSE, int K>
__global__ __launch_bounds__(1024, 4) void gemm_bt(
    const u16* __restrict__ A, const u16* __restrict__ Bm,
    const float* __restrict__ mask, void* __restrict__ Cout,
    const int M, const int N)
{
  constexpr int BK = 32;
  constexpr int NT = K / BK;
  constexpr int SLOT = 16384;                  // elems: A 8192 + B 8192 (32 KiB)
  __shared__ __align__(16) u16 lds[4 * SLOT];  // 128 KiB

  const int nbn = N / 256;
  const int nwg = (int)gridDim.x;
  const int cpx = nwg >> 3;
  const int bid = (int)blockIdx.x;
  const int swz = (bid & 7) * cpx + (bid >> 3);  // bijective XCD swizzle
  const int bm = (swz / nbn) * 256;
  const int bn = (swz % nbn) * 256;

  const int tid  = (int)threadIdx.x;
  const int lane = tid & 63;
  const int w    = tid >> 6;       // wave 0..15
  const int wr   = w >> 2;         // 0..3: 64-row group
  const int wc   = w & 3;          // 0..3: 64-col group

  const int fr = lane & 15;
  const int hi = lane >> 4;
  // lane-const read offset within a [256][32] block (proven conflict-free):
  // row fr(+16-aligned base), granule hi^((fr>>1)&3)
  const int rdc = fr * 32 + ((hi ^ ((fr >> 1) & 3)) * 8);

  // staging: thread covers row srow (0..255), inverse-swizzled source granule
  const int srow = tid >> 2;
  const int sq   = (tid & 3) ^ ((srow >> 1) & 3);
  const u16* aS = A  + (size_t)(bm + srow) * K + sq * 8;
  const u16* bS = Bm + (size_t)(bn + srow) * K + sq * 8;

#define STG_TILE(T, s) do {                                                   \
    u16* dst = lds + (s) * SLOT;                                              \
    const size_t ko = (size_t)(T) * BK;                                       \
    GLDS(aS + ko, dst +        tid * 8);                                      \
    GLDS(bS + ko, dst + 8192 + tid * 8);                                      \
  } while (0)

  f32x4 acc[4][4] = {};

  // ---- prologue: stage tiles 0,1,2 ----
  STG_TILE(0, 0);
  STG_TILE(1, 1);
  STG_TILE(2, 2);
  asm volatile("s_waitcnt vmcnt(4)" ::: "memory");   // tile 0 landed; 1,2 in flight
  BAR();

  // ---- main loop: one barrier per K-tile, free-running otherwise ----
#pragma unroll 4
  for (int t = 0; t < NT; ++t) {
    const u16* sA = lds + (t & 3) * SLOT;
    const u16* sB = sA + 8192;

    // [1] 8 fragment reads (conflict-free)
    s16x8 af[4], bf[4];
#pragma unroll
    for (int m = 0; m < 4; ++m)
      af[m] = *reinterpret_cast<const s16x8*>(&sA[(wr * 64 + m * 16) * 32 + rdc]);
#pragma unroll
    for (int n = 0; n < 4; ++n)
      bf[n] = *reinterpret_cast<const s16x8*>(&sB[(wc * 64 + n * 16) * 32 + rdc]);

    // [2] stage tile t+3 into slot (t-1)&3
    if (t + 3 < NT) STG_TILE(t + 3, (t + 3) & 3);

    // [3] 16 MFMA
    __builtin_amdgcn_s_setprio(1);
#pragma unroll
    for (int m = 0; m < 4; ++m)
#pragma unroll
      for (int n = 0; n < 4; ++n)
        acc[m][n] = __builtin_amdgcn_mfma_f32_16x16x32_bf16(
            af[m], bf[n], acc[m][n], 0, 0, 0);
    __builtin_amdgcn_s_setprio(0);

    // [4] counted drain: tile t+1 landed before next interval's reads
    if (t + 3 < NT)      asm volatile("s_waitcnt vmcnt(4)" ::: "memory");
    else if (t + 2 < NT) asm volatile("s_waitcnt vmcnt(2)" ::: "memory");
    else if (t + 1 < NT) asm volatile("s_waitcnt vmcnt(0)" ::: "memory");

    // [5] barrier
    if (t + 1 < NT) BAR();
  }
#undef STG_TILE

  // ---- epilogue: C/D layout col=lane&15, row=(lane>>4)*4 + j ----
  const int rgrp = hi * 4;
  if (FUSE) {
    u16* H = (u16*)Cout;
    const int ew = (bn + wc * 64) >> 6;  // wave's 64-col span = one expert
#pragma unroll
    for (int m = 0; m < 4; ++m) {
#pragma unroll
      for (int j = 0; j < 4; ++j) {
        const int grow = bm + wr * 64 + m * 16 + rgrp + j;
        const float mv = mask[(size_t)grow * NEXP + ew];
#pragma unroll
        for (int n = 0; n < 4; ++n) {
          const int gcol = bn + wc * 64 + n * 16 + fr;
          float v = acc[m][n][j];
          v = v / (1.0f + __expf(-v));   // silu
          H[(size_t)grow * N + gcol] = to_bf16(v * mv);
        }
      }
    }
  } else {
    float* O = (float*)Cout;
#pragma unroll
    for (int m = 0; m < 4; ++m) {
#pragma unroll
      for (int j = 0; j < 4; ++j) {
        const int grow = bm + wr * 64 + m * 16 + rgrp + j;
#pragma unroll
        for (int n = 0; n < 4; ++n) {
          const int gcol = bn + wc * 64 + n * 16 + fr;
          O[(size_t)grow * N + gcol] = acc[m][n][j];
        }
      }
    }
  }
}

extern "C" void kernel_launch(void* const* d_in, const int* in_sizes, int n_in,
                              void* d_out, int out_size, void* d_ws, size_t ws_size,
                              hipStream_t stream) {
  const float* x     = (const float*)d_in[0];
  const float* emask = (const float*)d_in[1];
  const float* w_up  = (const float*)d_in[2];
  const float* w_dn  = (const float*)d_in[3];
  float* out = (float*)d_out;

  // workspace (bf16): x[8192,2048] | w_up[4096,2048] | w_dn[2048,4096] | H[8192,4096]
  const size_t need = ((size_t)MT * DE + (size_t)ERDIM * DE + (size_t)DE * ERDIM +
                       (size_t)MT * ERDIM) * sizeof(u16);
  if (ws_size < need) return;

  u16* xb  = (u16*)d_ws;
  u16* wub = xb  + (size_t)MT * DE;
  u16* wdb = wub + (size_t)ERDIM * DE;
  u16* hb  = wdb + (size_t)DE * ERDIM;

  hipLaunchKernelGGL(cvt_all, dim3(2048), dim3(256), 0, stream,
                     x, xb, w_up, wub, w_dn, wdb);

  // GEMM1: H = silu(X @ Wup^T) * mask   [M=8192, N=4096, K=2048] -> 512 blocks
  hipLaunchKernelGGL((gemm_bt<1, DE>), dim3((MT / 256) * (ERDIM / 256)), dim3(1024), 0, stream,
                     xb, wub, emask, (void*)hb, MT, ERDIM);
  // GEMM2: out = H @ Wdown^T             [M=8192, N=2048, K=4096] -> 256 blocks
  hipLaunchKernelGGL((gemm_bt<0, ERDIM>), dim3((MT / 256) * (DE / 256)), dim3(1024), 0, stream,
                     hb, wdb, nullptr, (void*)out, MT, DE);
}

// Round 13
// 279.199 us; speedup vs baseline: 1.6099x; 1.6099x over previous
//
#include <hip/hip_runtime.h>
#include <hip/hip_bf16.h>

typedef unsigned short u16;
typedef unsigned int   u32;
typedef __attribute__((ext_vector_type(8))) short  s16x8;
typedef __attribute__((ext_vector_type(4))) float  f32x4;
typedef __attribute__((ext_vector_type(4))) unsigned short u16x4;

#define MT    8192   // B*S tokens
#define DE    2048   // embed dim
#define NEXP  64     // experts
#define ERDIM 4096   // experts * rank

// round-to-nearest-even f32 -> bf16
__device__ __forceinline__ u16 to_bf16(float f) {
  u32 u = __builtin_bit_cast(u32, f);
  u32 r = u + 0x7fffu + ((u >> 16) & 1u);
  return (u16)(r >> 16);
}

// one launch: convert x, w_up, w_dn f32 -> bf16 (grid-stride each)
__global__ void cvt_all(const float* __restrict__ x,  u16* __restrict__ xo,
                        const float* __restrict__ wu, u16* __restrict__ wuo,
                        const float* __restrict__ wd, u16* __restrict__ wdo) {
  const int stride = gridDim.x * blockDim.x;
  const int t0 = blockIdx.x * blockDim.x + threadIdx.x;
#define CVT_LOOP(src, dst, nq)                                                \
  for (int i = t0; i < (nq); i += stride) {                                   \
    const float4 v = *reinterpret_cast<const float4*>((src) + (size_t)i * 4); \
    u16x4 o;                                                                  \
    o.x = to_bf16(v.x); o.y = to_bf16(v.y);                                   \
    o.z = to_bf16(v.z); o.w = to_bf16(v.w);                                   \
    *reinterpret_cast<u16x4*>((dst) + (size_t)i * 4) = o;                     \
  }
  CVT_LOOP(x,  xo,  (MT * DE) / 4)
  CVT_LOOP(wu, wuo, (ERDIM * DE) / 4)
  CVT_LOOP(wd, wdo, (DE * ERDIM) / 4)
#undef CVT_LOOP
}

#define GLDS(gp, lp) __builtin_amdgcn_global_load_lds(                        \
    (const __attribute__((address_space(1))) void*)(gp),                      \
    (__attribute__((address_space(3))) void*)(lp), 16, 0, 0)

#define BAR() do { asm volatile("" ::: "memory");                             \
                   __builtin_amdgcn_s_barrier();                              \
                   asm volatile("" ::: "memory"); } while (0)

// FINAL (R3 config — best of 11 structures, 139 us/GEMM, 988 TF):
// C = A[M,K] * B[N,K]^T (bf16, row-major). 256x256 tile, BK=32, 8 waves (2Mx4N),
// 16x16x32 MFMA. 4-slot LDS ring (128 KiB), prefetch distance 3, counted vmcnt
// (8/4/0 cascade, never 0 mid-loop), ONE barrier per K-tile, free-running waves
// (m114 implicit overlap), setprio around MFMA. Conflict-free LDS: linear dest
// (global_load_lds) + inverse-swizzled per-lane global source + matching read
// XOR (SQ_LDS_BANK_CONFLICT == 0 measured across R2-R10).
// Slot safety: GLDS(t+3) targets slot (t-1)&3 whose readers finished before
// barrier(t-1); vmcnt(8) at tile end retires tile t+1 before its reads.
// FUSE=1: C_bf16[m,n] = bf16( silu(acc) * mask[m, n>>6] );  FUSE=0: C_f32 = acc
template<int FUSE, int K>
__global__ __launch_bounds__(512, 2) void gemm_bt(
    const u16* __restrict__ A, const u16* __restrict__ Bm,
    const float* __restrict__ mask, void* __restrict__ Cout,
    const int M, const int N)
{
  constexpr int BM = 256, BN = 256, BK = 32;
  constexpr int NT = K / BK;
  __shared__ __align__(16) u16 lds[65536];   // 4 slots x (A 8K elem + B 8K elem)

  const int nbn = N / BN;
  const int nwg = (int)gridDim.x;
  const int cpx = nwg >> 3;                      // nwg % 8 == 0 for all our grids
  const int bid = (int)blockIdx.x;
  const int swz = (bid & 7) * cpx + (bid >> 3);  // bijective XCD swizzle
  const int bm = (swz / nbn) * BM;
  const int bn = (swz % nbn) * BN;

  const int tid  = (int)threadIdx.x;
  const int lane = tid & 63;
  const int w    = tid >> 6;       // wave 0..7
  const int wr   = w >> 2;         // 0..1: M row-group (128 rows)
  const int wc   = w & 3;          // 0..3: N col-group (64 cols)

  const int fr = lane & 15;                          // fragment row
  const int cp = (lane >> 4) ^ ((lane >> 1) & 3);    // swizzled granule col (read)

  // staging: wave w owns chunks {2w, 2w+1} (16 rows x 64B each) of both A and B.
  // linear LDS dest (global_load_lds) + inverse-swizzled per-lane global source.
  const int lr = lane >> 2;                          // row within chunk
  const int cl = (lane & 3) ^ ((lane >> 3) & 3);     // logical granule col (source)
  const int c0 = 2 * w, c1 = 2 * w + 1;
  const u16* aS0 = A  + (size_t)(bm + c0 * 16 + lr) * K + cl * 8;
  const u16* aS1 = A  + (size_t)(bm + c1 * 16 + lr) * K + cl * 8;
  const u16* bS0 = Bm + (size_t)(bn + c0 * 16 + lr) * K + cl * 8;
  const u16* bS1 = Bm + (size_t)(bn + c1 * 16 + lr) * K + cl * 8;

  f32x4 acc[8][4] = {};

  // ---- prologue: stage tiles 0,1,2 (issue order = consumption order) ----
#pragma unroll
  for (int t = 0; t < 3; ++t) {
    u16* dst = lds + t * 16384;
    GLDS(aS0 + t * BK, dst +        c0 * 512);
    GLDS(aS1 + t * BK, dst +        c1 * 512);
    GLDS(bS0 + t * BK, dst + 8192 + c0 * 512);
    GLDS(bS1 + t * BK, dst + 8192 + c1 * 512);
  }
  asm volatile("s_waitcnt vmcnt(8)" ::: "memory");   // tile 0 landed; 1,2 in flight
  BAR();

  // ---- main loop: one barrier per K-tile, everything else free-running ----
#pragma unroll 4
  for (int t = 0; t < NT; ++t) {
    const u16* sA = lds + (t & 3) * 16384;
    const u16* sB = lds + (t & 3) * 16384 + 8192;

    // [1] all 12 fragment reads for tile t (proven conflict-free pattern)
    s16x8 afr[8], bfr[4];
#pragma unroll
    for (int m = 0; m < 8; ++m)
      afr[m] = *reinterpret_cast<const s16x8*>(
          &sA[(wr * 128 + m * 16 + fr) * 32 + cp * 8]);
#pragma unroll
    for (int n = 0; n < 4; ++n)
      bfr[n] = *reinterpret_cast<const s16x8*>(
          &sB[(wc * 64 + n * 16 + fr) * 32 + cp * 8]);

    // [2] stage tile t+3 into slot (t-1)&3
    if (t + 3 < NT) {
      u16* dst = lds + ((t + 3) & 3) * 16384;
      const size_t koff = (size_t)(t + 3) * BK;
      GLDS(aS0 + koff, dst +        c0 * 512);
      GLDS(aS1 + koff, dst +        c1 * 512);
      GLDS(bS0 + koff, dst + 8192 + c0 * 512);
      GLDS(bS1 + koff, dst + 8192 + c1 * 512);
    }

    // [3] MFMA cluster for tile t
    __builtin_amdgcn_s_setprio(1);
#pragma unroll
    for (int m = 0; m < 8; ++m)
#pragma unroll
      for (int n = 0; n < 4; ++n)
        acc[m][n] = __builtin_amdgcn_mfma_f32_16x16x32_bf16(
            afr[m], bfr[n], acc[m][n], 0, 0, 0);
    __builtin_amdgcn_s_setprio(0);

    // [4] counted tile-boundary drain (never 0 mid-loop)
    if (t + 3 < NT)      asm volatile("s_waitcnt vmcnt(8)" ::: "memory");
    else if (t + 2 < NT) asm volatile("s_waitcnt vmcnt(4)" ::: "memory");
    else if (t + 1 < NT) asm volatile("s_waitcnt vmcnt(0)" ::: "memory");

    // [5] barrier: cross-wave landing guarantee + slot-reuse fence
    if (t + 1 < NT) BAR();
  }

  // ---- epilogue: C/D layout col=lane&15, row=(lane>>4)*4 + j ----
  const int rgrp = (lane >> 4) * 4;
  if (FUSE) {
    u16* H = (u16*)Cout;
    const int ew = (bn + wc * 64) >> 6;  // wave's 64-col span = exactly one expert
#pragma unroll
    for (int m = 0; m < 8; ++m) {
#pragma unroll
      for (int j = 0; j < 4; ++j) {
        const int grow = bm + wr * 128 + m * 16 + rgrp + j;
        const float mv = mask[(size_t)grow * NEXP + ew];
#pragma unroll
        for (int n = 0; n < 4; ++n) {
          const int gcol = bn + wc * 64 + n * 16 + fr;
          float v = acc[m][n][j];
          v = v / (1.0f + __expf(-v));   // silu
          H[(size_t)grow * N + gcol] = to_bf16(v * mv);
        }
      }
    }
  } else {
    float* O = (float*)Cout;
#pragma unroll
    for (int m = 0; m < 8; ++m) {
#pragma unroll
      for (int j = 0; j < 4; ++j) {
        const int grow = bm + wr * 128 + m * 16 + rgrp + j;
#pragma unroll
        for (int n = 0; n < 4; ++n) {
          const int gcol = bn + wc * 64 + n * 16 + fr;
          O[(size_t)grow * N + gcol] = acc[m][n][j];
        }
      }
    }
  }
}

extern "C" void kernel_launch(void* const* d_in, const int* in_sizes, int n_in,
                              void* d_out, int out_size, void* d_ws, size_t ws_size,
                              hipStream_t stream) {
  const float* x     = (const float*)d_in[0];
  const float* emask = (const float*)d_in[1];
  const float* w_up  = (const float*)d_in[2];
  const float* w_dn  = (const float*)d_in[3];
  float* out = (float*)d_out;

  // workspace (bf16): x[8192,2048] | w_up[4096,2048] | w_dn[2048,4096] | H[8192,4096]
  const size_t need = ((size_t)MT * DE + (size_t)ERDIM * DE + (size_t)DE * ERDIM +
                       (size_t)MT * ERDIM) * sizeof(u16);
  if (ws_size < need) return;

  u16* xb  = (u16*)d_ws;
  u16* wub = xb  + (size_t)MT * DE;
  u16* wdb = wub + (size_t)ERDIM * DE;
  u16* hb  = wdb + (size_t)DE * ERDIM;

  hipLaunchKernelGGL(cvt_all, dim3(2048), dim3(256), 0, stream,
                     x, xb, w_up, wub, w_dn, wdb);

  // GEMM1: H = silu(X @ Wup^T) * mask   [M=8192, N=4096, K=2048] -> 512 blocks
  hipLaunchKernelGGL((gemm_bt<1, DE>), dim3((MT / 256) * (ERDIM / 256)), dim3(512), 0, stream,
                     xb, wub, emask, (void*)hb, MT, ERDIM);
  // GEMM2: out = H @ Wdown^T             [M=8192, N=2048, K=4096] -> 256 blocks
  hipLaunchKernelGGL((gemm_bt<0, ERDIM>), dim3((MT / 256) * (DE / 256)), dim3(512), 0, stream,
                     hb, wdb, nullptr, (void*)out, MT, DE);
}